// Round 1
// baseline (229.586 us; speedup 1.0000x reference)
//
#include <hip/hip_runtime.h>
#include <hip/hip_bf16.h>

// B=32, T=1024, D=256 fixed by the reference problem.
typedef __attribute__((ext_vector_type(8))) short bf16x8;
typedef __attribute__((ext_vector_type(4))) float f32x4;

#define INVT (1.0f/0.07f)

static __device__ __forceinline__ short f2bf(float f){
    unsigned int u = __float_as_uint(f);
    unsigned int r = (u + 0x7fffu + ((u >> 16) & 1u)) >> 16;
    return (short)r;
}

// ---- convert both weight matrices to bf16 (row-major [e][d], 256x256 each)
__global__ __launch_bounds__(256) void wconv_kernel(const float* __restrict__ Weeg,
                                                    const float* __restrict__ Weye,
                                                    short* __restrict__ Wout){
    int i = blockIdx.x * 256 + threadIdx.x;          // grid 512 -> 131072
    float v = (i < 65536) ? Weeg[i] : Weye[i - 65536];
    Wout[i] = f2bf(v);
}

// ---- per-batch rank scan: rank = cumsum(mask>0)-1, Tv = total valid
__global__ __launch_bounds__(256) void rank_kernel(const int* __restrict__ mask,
                                                   int* __restrict__ rank,
                                                   int* __restrict__ Tv){
    __shared__ int ssum[256];
    int b = blockIdx.x, tid = threadIdx.x;
    int local[4]; int s = 0;
    #pragma unroll
    for (int q = 0; q < 4; ++q){
        int t = tid*4 + q;
        local[q] = (mask[b*1024 + t] > 0) ? 1 : 0;
        s += local[q];
    }
    ssum[tid] = s;
    __syncthreads();
    for (int off = 1; off < 256; off <<= 1){
        int add = (tid >= off) ? ssum[tid - off] : 0;
        __syncthreads();
        ssum[tid] += add;
        __syncthreads();
    }
    int run = ssum[tid] - s;   // exclusive prefix of this thread's 4 elems
    #pragma unroll
    for (int q = 0; q < 4; ++q){
        run += local[q];
        rank[b*1024 + tid*4 + q] = run - 1;
    }
    if (tid == 255) Tv[b] = ssum[255];
}

// ---- projection + L2 normalize: Out[row][e] = bf16( (A[row]·W[e]) / max(||.||,1e-12) )
// grid.x = 512 (64-row tiles over 32768 rows), block 256 (4 waves, 16 rows/wave)
__global__ __launch_bounds__(256) void proj_kernel(const float* __restrict__ A,
                                                   const short* __restrict__ Wbf,
                                                   short* __restrict__ Out){
    int tid = threadIdx.x;
    int w   = tid >> 6;
    int lane = tid & 63;
    int l15 = lane & 15, lq = lane >> 4;
    int kb  = lq * 8;
    int row0 = blockIdx.x * 64;

    // A-fragments: lane reads A[row0 + w*16 + l15][g*32 + kb .. +7] (f32 -> bf16)
    bf16x8 af[8];
    {
        const float* ap = A + (size_t)(row0 + w*16 + l15) * 256 + kb;
        #pragma unroll
        for (int g = 0; g < 8; ++g){
            float4 x0 = *(const float4*)(ap + g*32);
            float4 x1 = *(const float4*)(ap + g*32 + 4);
            bf16x8 t;
            t[0]=f2bf(x0.x); t[1]=f2bf(x0.y); t[2]=f2bf(x0.z); t[3]=f2bf(x0.w);
            t[4]=f2bf(x1.x); t[5]=f2bf(x1.y); t[6]=f2bf(x1.z); t[7]=f2bf(x1.w);
            af[g] = t;
        }
    }

    f32x4 acc[16];
    #pragma unroll
    for (int nt = 0; nt < 16; ++nt){
        f32x4 c = {0.f, 0.f, 0.f, 0.f};
        const short* wp = Wbf + (nt*16 + l15) * 256 + kb;
        #pragma unroll
        for (int g = 0; g < 8; ++g){
            bf16x8 bf = *(const bf16x8*)(wp + g*32);
            c = __builtin_amdgcn_mfma_f32_16x16x32_bf16(af[g], bf, c, 0, 0, 0);
        }
        acc[nt] = c;
    }

    // per-row sum of squares: row = w*16 + lq*4 + r; cols of this lane: nt*16+l15
    float scale[4];
    #pragma unroll
    for (int r = 0; r < 4; ++r){
        float ss = 0.f;
        #pragma unroll
        for (int nt = 0; nt < 16; ++nt){ float x = acc[nt][r]; ss += x*x; }
        ss += __shfl_xor(ss, 1);
        ss += __shfl_xor(ss, 2);
        ss += __shfl_xor(ss, 4);
        ss += __shfl_xor(ss, 8);
        float nrm = sqrtf(ss);
        scale[r] = 1.0f / fmaxf(nrm, 1e-12f);
    }

    short* op = Out + (size_t)(row0 + w*16) * 256;
    #pragma unroll
    for (int nt = 0; nt < 16; ++nt){
        #pragma unroll
        for (int r = 0; r < 4; ++r){
            op[(lq*4 + r) * 256 + nt*16 + l15] = f2bf(acc[nt][r] * scale[r]);
        }
    }
}

// ---- flash-style loss: per (b, 64-row i-tile) block; j-chunks of 64 staged in LDS.
// Per valid row i: lse = log(sum_{valid j} exp(s_ij)), pos = max over banded valid j.
// Accumulate sum over valid i of (lse - pos) into bacc[b].
__global__ __launch_bounds__(256) void loss_kernel(const short* __restrict__ E,
                                                   const short* __restrict__ V,
                                                   const int* __restrict__ maskg,
                                                   const int* __restrict__ rankg,
                                                   float* __restrict__ bacc){
    __shared__ short sV[64 * 264];         // padded stride 264 (2-way bank alias = free)
    __shared__ short sRank[1024];
    __shared__ unsigned char sValid[1024];

    int b  = blockIdx.y;
    int i0 = blockIdx.x * 64;
    int tid = threadIdx.x;
    int w = tid >> 6, lane = tid & 63;
    int l15 = lane & 15, lq = lane >> 4;
    int kb = lq * 8;

    #pragma unroll
    for (int q = 0; q < 4; ++q){
        int t = q*256 + tid;
        sRank[t]  = (short)rankg[b*1024 + t];
        sValid[t] = (maskg[b*1024 + t] > 0) ? 1 : 0;
    }

    // A-fragments for this wave's 16 i-rows, straight from global bf16 E
    bf16x8 af[8];
    {
        const short* ep = E + (size_t)(b*1024 + i0 + w*16 + l15) * 256 + kb;
        #pragma unroll
        for (int g = 0; g < 8; ++g) af[g] = *(const bf16x8*)(ep + g*32);
    }
    __syncthreads();

    bool vi[4]; int ri[4];
    #pragma unroll
    for (int r = 0; r < 4; ++r){
        int irow = i0 + w*16 + lq*4 + r;
        vi[r] = sValid[irow] != 0;
        ri[r] = sRank[irow];
    }

    float lsum[4] = {0.f, 0.f, 0.f, 0.f};
    float pmax[4] = {-1e30f, -1e30f, -1e30f, -1e30f};
    const short* vb = V + (size_t)b * 1024 * 256;

    for (int jc = 0; jc < 16; ++jc){
        if (jc) __syncthreads();
        // stage 64x256 bf16 chunk of V
        #pragma unroll
        for (int p = 0; p < 8; ++p){
            int flat = p*2048 + tid*8;
            int row = flat >> 8, col = flat & 255;
            *(int4*)&sV[row*264 + col] = *(const int4*)(vb + (size_t)(jc*64 + row)*256 + col);
        }
        __syncthreads();

        #pragma unroll
        for (int jt = 0; jt < 4; ++jt){
            f32x4 c = {0.f, 0.f, 0.f, 0.f};
            const short* vp = &sV[(jt*16 + l15) * 264 + kb];
            #pragma unroll
            for (int g = 0; g < 8; ++g){
                bf16x8 bf = *(const bf16x8*)(vp + g*32);
                c = __builtin_amdgcn_mfma_f32_16x16x32_bf16(af[g], bf, c, 0, 0, 0);
            }
            int j = jc*64 + jt*16 + l15;
            bool vjv = sValid[j] != 0;
            int  rj  = sRank[j];
            if (vjv){
                #pragma unroll
                for (int r = 0; r < 4; ++r){
                    float s = c[r] * INVT;
                    lsum[r] += __expf(s);
                    int d = ri[r] - rj; if (d < 0) d = -d;
                    if (vi[r] && d <= 2) pmax[r] = fmaxf(pmax[r], s);
                }
            }
        }
    }

    // reduce across the 16 lanes sharing each row
    #pragma unroll
    for (int r = 0; r < 4; ++r){
        float l = lsum[r], pm = pmax[r];
        #pragma unroll
        for (int m = 1; m < 16; m <<= 1){
            l  += __shfl_xor(l, m);
            pm  = fmaxf(pm, __shfl_xor(pm, m));
        }
        lsum[r] = l; pmax[r] = pm;
    }

    float contrib = 0.f;
    if (l15 == 0){
        #pragma unroll
        for (int r = 0; r < 4; ++r)
            if (vi[r]) contrib += logf(lsum[r]) - pmax[r];
    }
    contrib += __shfl_xor(contrib, 16);
    contrib += __shfl_xor(contrib, 32);
    if (lane == 0) atomicAdd(&bacc[b], contrib);
}

// ---- final: out = sum_b (Tv>=2 ? bacc/Tv : 0) / 32
__global__ void final_kernel(const float* __restrict__ bacc,
                             const int* __restrict__ Tv,
                             float* __restrict__ out){
    int tid = threadIdx.x;
    float v = 0.f;
    if (tid < 32){
        int tv = Tv[tid];
        if (tv >= 2) v = bacc[tid] / (float)tv;
    }
    #pragma unroll
    for (int m = 1; m < 64; m <<= 1) v += __shfl_xor(v, m);
    if (tid == 0) out[0] = v / 32.0f;
}

extern "C" void kernel_launch(void* const* d_in, const int* in_sizes, int n_in,
                              void* d_out, int out_size, void* d_ws, size_t ws_size,
                              hipStream_t stream) {
    const float* eeg  = (const float*)d_in[0];
    const float* eye  = (const float*)d_in[1];
    const int*   mask = (const int*)d_in[2];
    const float* Weeg = (const float*)d_in[3];
    const float* Weye = (const float*)d_in[4];
    float* out = (float*)d_out;

    char* ws = (char*)d_ws;
    short* e_bf = (short*)(ws);                          // 32768*256*2 = 16 MiB
    short* v_bf = (short*)(ws + 16777216);               // 16 MiB
    short* wbf  = (short*)(ws + 33554432);               // 256 KiB (both W's)
    int*   rank = (int*)  (ws + 33816576);               // 128 KiB
    int*   Tv   = (int*)  (ws + 33947648);               // 128 B
    float* bacc = (float*)(ws + 33947776);               // 128 B

    hipMemsetAsync(bacc, 0, 32 * sizeof(float), stream);

    wconv_kernel<<<512, 256, 0, stream>>>(Weeg, Weye, wbf);
    rank_kernel<<<32, 256, 0, stream>>>(mask, rank, Tv);
    proj_kernel<<<512, 256, 0, stream>>>(eeg, wbf,         e_bf);
    proj_kernel<<<512, 256, 0, stream>>>(eye, wbf + 65536, v_bf);
    loss_kernel<<<dim3(16, 32), 256, 0, stream>>>(e_bf, v_bf, mask, rank, bacc);
    final_kernel<<<1, 64, 0, stream>>>(bacc, Tv, out);
}

// Round 2
// 186.577 us; speedup vs baseline: 1.2305x; 1.2305x over previous
//
#include <hip/hip_runtime.h>
#include <hip/hip_bf16.h>

// B=32, T=1024, D=256 fixed by the reference problem.
typedef __attribute__((ext_vector_type(8))) short bf16x8;
typedef __attribute__((ext_vector_type(4))) float f32x4;

#define INVT (1.0f/0.07f)

static __device__ __forceinline__ short f2bf(float f){
    unsigned int u = __float_as_uint(f);
    unsigned int r = (u + 0x7fffu + ((u >> 16) & 1u)) >> 16;
    return (short)r;
}
static __device__ __forceinline__ float bf2f(short s){
    return __uint_as_float(((unsigned int)(unsigned short)s) << 16);
}

// ---- convert both weight matrices to bf16 (row-major [e][d], 256x256 each)
__global__ __launch_bounds__(256) void wconv_kernel(const float* __restrict__ Weeg,
                                                    const float* __restrict__ Weye,
                                                    short* __restrict__ Wout){
    int i = blockIdx.x * 256 + threadIdx.x;          // grid 512 -> 131072
    float v = (i < 65536) ? Weeg[i] : Weye[i - 65536];
    Wout[i] = f2bf(v);
}

// ---- per-batch rank scan: rank = cumsum(valid)-1, idx[rank]=t scatter, cb bias, Tv
__global__ __launch_bounds__(256) void rank_kernel(const int* __restrict__ mask,
                                                   int* __restrict__ rank,
                                                   int* __restrict__ idx,
                                                   int* __restrict__ Tv,
                                                   float* __restrict__ cb){
    __shared__ int ssum[256];
    int b = blockIdx.x, tid = threadIdx.x;
    int local[4]; int s = 0;
    #pragma unroll
    for (int q = 0; q < 4; ++q){
        int t = tid*4 + q;
        local[q] = (mask[b*1024 + t] > 0) ? 1 : 0;
        s += local[q];
    }
    ssum[tid] = s;
    __syncthreads();
    for (int off = 1; off < 256; off <<= 1){
        int add = (tid >= off) ? ssum[tid - off] : 0;
        __syncthreads();
        ssum[tid] += add;
        __syncthreads();
    }
    int run = ssum[tid] - s;   // exclusive prefix of this thread's 4 elems
    #pragma unroll
    for (int q = 0; q < 4; ++q){
        int t = tid*4 + q;
        int g = b*1024 + t;
        run += local[q];
        rank[g] = run - 1;
        cb[g]   = local[q] ? 0.0f : -1e9f;
        if (local[q]) idx[b*1024 + run - 1] = t;
    }
    if (tid == 255) Tv[b] = ssum[255];
}

// ---- fused projection + L2 normalize for BOTH modalities (blockIdx.y selects).
// Block: 64 rows, 4 waves x 16 rows. W staged in LDS in 4 passes of 64 out-cols.
__global__ __launch_bounds__(256, 3) void proj_kernel(const float* __restrict__ Aeeg,
                                                      const float* __restrict__ Aeye,
                                                      const short* __restrict__ Wbf,
                                                      short* __restrict__ Eout,
                                                      short* __restrict__ Vout){
    __shared__ short sW[64 * 264];
    int sel = blockIdx.y;
    const float* A   = sel ? Aeye : Aeeg;
    const short* W   = Wbf + sel * 65536;
    short*       Out = sel ? Vout : Eout;

    int tid = threadIdx.x;
    int w = tid >> 6, lane = tid & 63;
    int l15 = lane & 15, lq = lane >> 4;
    int kb  = lq * 8;
    int row0 = blockIdx.x * 64;

    // A-fragments for this wave's 16 rows (f32 -> bf16), held across all passes
    bf16x8 af[8];
    {
        const float* ap = A + (size_t)(row0 + w*16 + l15) * 256 + kb;
        #pragma unroll
        for (int g = 0; g < 8; ++g){
            float4 x0 = *(const float4*)(ap + g*32);
            float4 x1 = *(const float4*)(ap + g*32 + 4);
            bf16x8 t;
            t[0]=f2bf(x0.x); t[1]=f2bf(x0.y); t[2]=f2bf(x0.z); t[3]=f2bf(x0.w);
            t[4]=f2bf(x1.x); t[5]=f2bf(x1.y); t[6]=f2bf(x1.z); t[7]=f2bf(x1.w);
            af[g] = t;
        }
    }

    f32x4 acc[16];
    #pragma unroll
    for (int q = 0; q < 16; ++q) acc[q] = (f32x4){0.f,0.f,0.f,0.f};

    for (int pass = 0; pass < 4; ++pass){
        if (pass) __syncthreads();
        // stage W rows [pass*64, +64): 64x256 bf16
        #pragma unroll
        for (int p = 0; p < 8; ++p){
            int flat = p*2048 + tid*8;
            int r = flat >> 8, c = flat & 255;
            *(int4*)&sW[r*264 + c] = *(const int4*)(W + (size_t)(pass*64 + r)*256 + c);
        }
        __syncthreads();
        #pragma unroll
        for (int nt = 0; nt < 4; ++nt){
            f32x4 c = acc[pass*4 + nt];
            const short* wp = &sW[(nt*16 + l15) * 264 + kb];
            #pragma unroll
            for (int g = 0; g < 8; ++g){
                bf16x8 bf = *(const bf16x8*)(wp + g*32);
                c = __builtin_amdgcn_mfma_f32_16x16x32_bf16(af[g], bf, c, 0, 0, 0);
            }
            acc[pass*4 + nt] = c;
        }
    }

    // per-row sum of squares: row = w*16 + lq*4 + r; lane's cols: q*16 + l15
    float scale[4];
    #pragma unroll
    for (int r = 0; r < 4; ++r){
        float ss = 0.f;
        #pragma unroll
        for (int q = 0; q < 16; ++q){ float x = acc[q][r]; ss += x*x; }
        ss += __shfl_xor(ss, 1);
        ss += __shfl_xor(ss, 2);
        ss += __shfl_xor(ss, 4);
        ss += __shfl_xor(ss, 8);
        scale[r] = 1.0f / fmaxf(sqrtf(ss), 1e-12f);
    }

    short* op = Out + (size_t)(row0 + w*16) * 256;
    #pragma unroll
    for (int q = 0; q < 16; ++q){
        #pragma unroll
        for (int r = 0; r < 4; ++r){
            op[(lq*4 + r) * 256 + q*16 + l15] = f2bf(acc[q][r] * scale[r]);
        }
    }
}

// ---- loss: per (b, 128-row i-block, 256-col j-slice) block. Each wave: 32 i-rows.
// Computes partial exp-sums per row into psum[b][js][i]; no band/max logic here.
__global__ __launch_bounds__(256, 3) void loss_kernel(const short* __restrict__ E,
                                                      const short* __restrict__ V,
                                                      const float* __restrict__ cb,
                                                      float* __restrict__ psum){
    __shared__ short sV[64 * 264];
    __shared__ float sCb[256];

    int ib = blockIdx.x;            // 0..7  (128 i-rows each)
    int js = blockIdx.y;            // 0..3  (256 j-cols each)
    int b  = blockIdx.z;            // 0..31
    int i0 = ib * 128;

    int tid = threadIdx.x;
    int w = tid >> 6, lane = tid & 63;
    int l15 = lane & 15, lq = lane >> 4;
    int kb = lq * 8;

    sCb[tid] = cb[b*1024 + js*256 + tid];

    // A-fragments: two 16-row sets -> 32 i-rows per wave
    bf16x8 af0[8], af1[8];
    {
        const short* ep = E + ((size_t)b*1024 + i0 + w*32 + l15) * 256 + kb;
        #pragma unroll
        for (int g = 0; g < 8; ++g){
            af0[g] = *(const bf16x8*)(ep + g*32);
            af1[g] = *(const bf16x8*)(ep + 16*256 + g*32);
        }
    }

    float ls0[4] = {0.f,0.f,0.f,0.f};
    float ls1[4] = {0.f,0.f,0.f,0.f};
    const short* vb = V + ((size_t)b*1024 + js*256) * 256;

    for (int jc = 0; jc < 4; ++jc){
        __syncthreads();
        #pragma unroll
        for (int p = 0; p < 8; ++p){
            int flat = p*2048 + tid*8;
            int r = flat >> 8, c = flat & 255;
            *(int4*)&sV[r*264 + c] = *(const int4*)(vb + (size_t)(jc*64 + r)*256 + c);
        }
        __syncthreads();

        #pragma unroll
        for (int jt = 0; jt < 4; ++jt){
            f32x4 c0 = {0.f,0.f,0.f,0.f};
            f32x4 c1 = {0.f,0.f,0.f,0.f};
            const short* vp = &sV[(jt*16 + l15) * 264 + kb];
            #pragma unroll
            for (int g = 0; g < 8; ++g){
                bf16x8 bf = *(const bf16x8*)(vp + g*32);
                c0 = __builtin_amdgcn_mfma_f32_16x16x32_bf16(af0[g], bf, c0, 0, 0, 0);
                c1 = __builtin_amdgcn_mfma_f32_16x16x32_bf16(af1[g], bf, c1, 0, 0, 0);
            }
            float cbj = sCb[jc*64 + jt*16 + l15];
            #pragma unroll
            for (int r = 0; r < 4; ++r){
                ls0[r] += __expf(fmaf(c0[r], INVT, cbj));
                ls1[r] += __expf(fmaf(c1[r], INVT, cbj));
            }
        }
    }

    // reduce across the 16 lanes sharing each row
    #pragma unroll
    for (int r = 0; r < 4; ++r){
        #pragma unroll
        for (int m = 1; m < 16; m <<= 1){
            ls0[r] += __shfl_xor(ls0[r], m);
            ls1[r] += __shfl_xor(ls1[r], m);
        }
    }
    if (l15 == 0){
        float* pp = psum + (((size_t)(b*4 + js)) << 10);
        int ibase = i0 + w*32 + lq*4;
        #pragma unroll
        for (int r = 0; r < 4; ++r){
            pp[ibase + r]      = ls0[r];
            pp[ibase + 16 + r] = ls1[r];
        }
    }
}

// ---- banded positive max: per valid row, <=5 candidate columns via rank index list.
// One 16-lane group per row; each group handles 8 rows (grid 256 x 256 threads).
__global__ __launch_bounds__(256) void pos_kernel(const short* __restrict__ E,
                                                  const short* __restrict__ V,
                                                  const int* __restrict__ mask,
                                                  const int* __restrict__ rank,
                                                  const int* __restrict__ idx,
                                                  const int* __restrict__ Tv,
                                                  float* __restrict__ pmax){
    int tid = threadIdx.x;
    int gl  = tid & 15;
    int gid = (blockIdx.x * 256 + tid) >> 4;   // 0..4095

    for (int q = 0; q < 8; ++q){
        int rf = gid + q * 4096;               // 0..32767
        int b  = rf >> 10;
        if (mask[rf] > 0){
            int ri = rank[rf];
            int tv = Tv[b];
            int lo = ri - 2; if (lo < 0) lo = 0;
            int hi = ri + 2; if (hi > tv - 1) hi = tv - 1;

            const short* epp = E + (size_t)rf * 256 + gl * 16;
            float ev[16];
            {
                bf16x8 e0 = *(const bf16x8*)epp;
                bf16x8 e1 = *(const bf16x8*)(epp + 8);
                #pragma unroll
                for (int k = 0; k < 8; ++k){ ev[k] = bf2f(e0[k]); ev[8+k] = bf2f(e1[k]); }
            }
            float pm = -1e30f;
            for (int r = lo; r <= hi; ++r){
                int j = idx[b*1024 + r];
                const short* vpp = V + ((size_t)(b*1024) + j) * 256 + gl * 16;
                bf16x8 v0 = *(const bf16x8*)vpp;
                bf16x8 v1 = *(const bf16x8*)(vpp + 8);
                float s = 0.f;
                #pragma unroll
                for (int k = 0; k < 8; ++k){
                    s = fmaf(ev[k],   bf2f(v0[k]), s);
                    s = fmaf(ev[8+k], bf2f(v1[k]), s);
                }
                s += __shfl_xor(s, 1);
                s += __shfl_xor(s, 2);
                s += __shfl_xor(s, 4);
                s += __shfl_xor(s, 8);
                pm = fmaxf(pm, s);
            }
            if (gl == 0) pmax[rf] = pm * INVT;
        }
    }
}

// ---- per-batch reduce: sum over valid i of (log(sum_js psum) - pmax); gate Tv>=2
__global__ __launch_bounds__(256) void reduce_kernel(const float* __restrict__ psum,
                                                     const float* __restrict__ pmax,
                                                     const int* __restrict__ mask,
                                                     const int* __restrict__ Tv,
                                                     float* __restrict__ per_b){
    __shared__ float sred[4];
    int b = blockIdx.x, tid = threadIdx.x;
    float a = 0.f;
    const float* pp = psum + (((size_t)(b*4)) << 10);
    #pragma unroll
    for (int q = 0; q < 4; ++q){
        int i = q*256 + tid;
        int g = b*1024 + i;
        if (mask[g] > 0){
            float ps = pp[i] + pp[i + 1024] + pp[i + 2048] + pp[i + 3072];
            a += logf(ps) - pmax[g];
        }
    }
    #pragma unroll
    for (int m = 1; m < 64; m <<= 1) a += __shfl_xor(a, m);
    if ((tid & 63) == 0) sred[tid >> 6] = a;
    __syncthreads();
    if (tid == 0){
        float t = sred[0] + sred[1] + sred[2] + sred[3];
        int tv = Tv[b];
        per_b[b] = (tv >= 2) ? t / (float)tv : 0.f;
    }
}

// ---- final: out = sum_b per_b / 32
__global__ void final_kernel(const float* __restrict__ per_b,
                             float* __restrict__ out){
    int tid = threadIdx.x;
    float v = (tid < 32) ? per_b[tid] : 0.f;
    #pragma unroll
    for (int m = 1; m < 64; m <<= 1) v += __shfl_xor(v, m);
    if (tid == 0) out[0] = v / 32.0f;
}

extern "C" void kernel_launch(void* const* d_in, const int* in_sizes, int n_in,
                              void* d_out, int out_size, void* d_ws, size_t ws_size,
                              hipStream_t stream) {
    const float* eeg  = (const float*)d_in[0];
    const float* eye  = (const float*)d_in[1];
    const int*   mask = (const int*)d_in[2];
    const float* Weeg = (const float*)d_in[3];
    const float* Weye = (const float*)d_in[4];
    float* out = (float*)d_out;

    char* ws = (char*)d_ws;
    short* e_bf  = (short*)(ws);                       // 16 MiB
    short* v_bf  = (short*)(ws + 16777216);            // 16 MiB
    short* wbf   = (short*)(ws + 33554432);            // 256 KiB
    int*   rank  = (int*)  (ws + 33816576);            // 128 KiB
    int*   idx   = (int*)  (ws + 33947648);            // 128 KiB
    float* cb    = (float*)(ws + 34078720);            // 128 KiB
    float* psum  = (float*)(ws + 34209792);            // 512 KiB
    float* pmax  = (float*)(ws + 34734080);            // 128 KiB
    int*   Tv    = (int*)  (ws + 34865152);            // 128 B
    float* per_b = (float*)(ws + 34865280);            // 128 B

    wconv_kernel<<<512, 256, 0, stream>>>(Weeg, Weye, wbf);
    rank_kernel<<<32, 256, 0, stream>>>(mask, rank, idx, Tv, cb);
    proj_kernel<<<dim3(512, 2), 256, 0, stream>>>(eeg, eye, wbf, e_bf, v_bf);
    loss_kernel<<<dim3(8, 4, 32), 256, 0, stream>>>(e_bf, v_bf, cb, psum);
    pos_kernel<<<256, 256, 0, stream>>>(e_bf, v_bf, mask, rank, idx, Tv, pmax);
    reduce_kernel<<<32, 256, 0, stream>>>(psum, pmax, mask, Tv, per_b);
    final_kernel<<<1, 64, 0, stream>>>(per_b, out);
}

// Round 3
// 177.485 us; speedup vs baseline: 1.2936x; 1.0512x over previous
//
#include <hip/hip_runtime.h>
#include <hip/hip_bf16.h>

// B=32, T=1024, D=256 fixed by the reference problem.
typedef __attribute__((ext_vector_type(8))) short bf16x8;
typedef __attribute__((ext_vector_type(4))) float f32x4;

#define INVT (1.0f/0.07f)

static __device__ __forceinline__ short f2bf(float f){
    unsigned int u = __float_as_uint(f);
    unsigned int r = (u + 0x7fffu + ((u >> 16) & 1u)) >> 16;
    return (short)r;
}
static __device__ __forceinline__ float bf2f(short s){
    return __uint_as_float(((unsigned int)(unsigned short)s) << 16);
}

// ---- prep: blocks 0..511 convert W to bf16; blocks 512..543 do per-batch rank scan
__global__ __launch_bounds__(256) void prep_kernel(const float* __restrict__ Weeg,
                                                   const float* __restrict__ Weye,
                                                   const int* __restrict__ mask,
                                                   short* __restrict__ Wout,
                                                   int* __restrict__ rank,
                                                   int* __restrict__ idx,
                                                   int* __restrict__ Tv,
                                                   float* __restrict__ cb){
    __shared__ int ssum[256];
    int tid = threadIdx.x;
    if (blockIdx.x < 512){
        int i = blockIdx.x * 256 + tid;
        float v = (i < 65536) ? Weeg[i] : Weye[i - 65536];
        Wout[i] = f2bf(v);
        return;
    }
    int b = blockIdx.x - 512;
    int local[4]; int s = 0;
    #pragma unroll
    for (int q = 0; q < 4; ++q){
        int t = tid*4 + q;
        local[q] = (mask[b*1024 + t] > 0) ? 1 : 0;
        s += local[q];
    }
    ssum[tid] = s;
    __syncthreads();
    for (int off = 1; off < 256; off <<= 1){
        int add = (tid >= off) ? ssum[tid - off] : 0;
        __syncthreads();
        ssum[tid] += add;
        __syncthreads();
    }
    int run = ssum[tid] - s;
    #pragma unroll
    for (int q = 0; q < 4; ++q){
        int t = tid*4 + q;
        int g = b*1024 + t;
        run += local[q];
        rank[g] = run - 1;
        cb[g]   = local[q] ? 0.0f : -1e9f;
        if (local[q]) idx[b*1024 + run - 1] = t;
    }
    if (tid == 255) Tv[b] = ssum[255];
}

// ---- fused projection + L2 normalize, both modalities (blockIdx.y selects).
// Swapped operands: W rows are the MFMA A-operand -> each lane holds 4 consecutive
// e-columns per tile -> packed short4 (8B) stores. 64 x-rows/block, 4 waves x 16.
__global__ __launch_bounds__(256, 3) void proj_kernel(const float* __restrict__ Aeeg,
                                                      const float* __restrict__ Aeye,
                                                      const short* __restrict__ Wbf,
                                                      short* __restrict__ Eout,
                                                      short* __restrict__ Vout){
    __shared__ short sW[64 * 264];
    int sel = blockIdx.y;
    const float* A   = sel ? Aeye : Aeeg;
    const short* W   = Wbf + sel * 65536;
    short*       Out = sel ? Vout : Eout;

    int tid = threadIdx.x;
    int w = tid >> 6, lane = tid & 63;
    int l15 = lane & 15, lq = lane >> 4;
    int kb  = lq * 8;
    int row0 = blockIdx.x * 64;

    // X-row fragments (B-operand): lane reads X[row0 + w*16 + l15][kb + g*32 ..+7]
    bf16x8 xf[8];
    {
        const float* ap = A + (size_t)(row0 + w*16 + l15) * 256 + kb;
        #pragma unroll
        for (int g = 0; g < 8; ++g){
            float4 x0 = *(const float4*)(ap + g*32);
            float4 x1 = *(const float4*)(ap + g*32 + 4);
            bf16x8 t;
            t[0]=f2bf(x0.x); t[1]=f2bf(x0.y); t[2]=f2bf(x0.z); t[3]=f2bf(x0.w);
            t[4]=f2bf(x1.x); t[5]=f2bf(x1.y); t[6]=f2bf(x1.z); t[7]=f2bf(x1.w);
            xf[g] = t;
        }
    }

    f32x4 acc[16];
    #pragma unroll
    for (int q = 0; q < 16; ++q) acc[q] = (f32x4){0.f,0.f,0.f,0.f};

    #pragma unroll
    for (int pass = 0; pass < 4; ++pass){
        if (pass) __syncthreads();
        // stage W rows [pass*64, +64): 64x256 bf16
        #pragma unroll
        for (int p = 0; p < 8; ++p){
            int flat = p*2048 + tid*8;
            int r = flat >> 8, c = flat & 255;
            *(int4*)&sW[r*264 + c] = *(const int4*)(W + (size_t)(pass*64 + r)*256 + c);
        }
        __syncthreads();
        #pragma unroll
        for (int nt = 0; nt < 4; ++nt){
            f32x4 c = acc[pass*4 + nt];
            const short* wp = &sW[(nt*16 + l15) * 264 + kb];
            #pragma unroll
            for (int g = 0; g < 8; ++g){
                bf16x8 wf = *(const bf16x8*)(wp + g*32);
                c = __builtin_amdgcn_mfma_f32_16x16x32_bf16(wf, xf[g], c, 0, 0, 0);
            }
            acc[pass*4 + nt] = c;
        }
    }

    // D[e][xrow]: lane holds xrow = l15, e = tile*16 + lq*4 + r.
    // sum of squares of this lane's 64 e-values, then reduce across the 4 lq groups
    float ss = 0.f;
    #pragma unroll
    for (int q = 0; q < 16; ++q){
        #pragma unroll
        for (int r = 0; r < 4; ++r){ float x = acc[q][r]; ss += x*x; }
    }
    ss += __shfl_xor(ss, 16);
    ss += __shfl_xor(ss, 32);
    float scale = 1.0f / fmaxf(sqrtf(ss), 1e-12f);

    short* op = Out + (size_t)(row0 + w*16 + l15) * 256 + lq*4;
    #pragma unroll
    for (int q = 0; q < 16; ++q){
        short4 pk;
        pk.x = f2bf(acc[q][0] * scale);
        pk.y = f2bf(acc[q][1] * scale);
        pk.z = f2bf(acc[q][2] * scale);
        pk.w = f2bf(acc[q][3] * scale);
        *(short4*)(op + ((q >> 2) * 64 + (q & 3) * 16)) = pk;
    }
}

// ---- loss: per (b, 256-row i-block, 256-col j-slice) block. Each wave: 64 i-rows
// (4 A-sets -> each LDS B-frag feeds 4 MFMAs). Partial exp-sums -> psum[b][js][i].
__global__ __launch_bounds__(256, 2) void loss_kernel(const short* __restrict__ E,
                                                      const short* __restrict__ V,
                                                      const float* __restrict__ cb,
                                                      float* __restrict__ psum){
    __shared__ short sV[64 * 264];
    __shared__ float sCb[256];

    int ib = blockIdx.x;            // 0..3  (256 i-rows each)
    int js = blockIdx.y;            // 0..3  (256 j-cols each)
    int b  = blockIdx.z;            // 0..31
    int i0 = ib * 256;

    int tid = threadIdx.x;
    int w = tid >> 6, lane = tid & 63;
    int l15 = lane & 15, lq = lane >> 4;
    int kb = lq * 8;

    sCb[tid] = cb[b*1024 + js*256 + tid];

    // A-fragments: four 16-row sets -> 64 i-rows per wave
    bf16x8 af[4][8];
    {
        const short* ep = E + ((size_t)b*1024 + i0 + w*64 + l15) * 256 + kb;
        #pragma unroll
        for (int s = 0; s < 4; ++s){
            #pragma unroll
            for (int g = 0; g < 8; ++g)
                af[s][g] = *(const bf16x8*)(ep + s*16*256 + g*32);
        }
    }

    float ls[4][4];
    #pragma unroll
    for (int s = 0; s < 4; ++s)
        #pragma unroll
        for (int r = 0; r < 4; ++r) ls[s][r] = 0.f;

    const short* vb = V + ((size_t)b*1024 + js*256) * 256;

    #pragma unroll
    for (int jc = 0; jc < 4; ++jc){
        __syncthreads();
        #pragma unroll
        for (int p = 0; p < 8; ++p){
            int flat = p*2048 + tid*8;
            int r = flat >> 8, c = flat & 255;
            *(int4*)&sV[r*264 + c] = *(const int4*)(vb + (size_t)(jc*64 + r)*256 + c);
        }
        __syncthreads();

        #pragma unroll
        for (int jt = 0; jt < 4; ++jt){
            f32x4 c0 = {0.f,0.f,0.f,0.f};
            f32x4 c1 = {0.f,0.f,0.f,0.f};
            f32x4 c2 = {0.f,0.f,0.f,0.f};
            f32x4 c3 = {0.f,0.f,0.f,0.f};
            const short* vp = &sV[(jt*16 + l15) * 264 + kb];
            #pragma unroll
            for (int g = 0; g < 8; ++g){
                bf16x8 bf = *(const bf16x8*)(vp + g*32);
                c0 = __builtin_amdgcn_mfma_f32_16x16x32_bf16(af[0][g], bf, c0, 0, 0, 0);
                c1 = __builtin_amdgcn_mfma_f32_16x16x32_bf16(af[1][g], bf, c1, 0, 0, 0);
                c2 = __builtin_amdgcn_mfma_f32_16x16x32_bf16(af[2][g], bf, c2, 0, 0, 0);
                c3 = __builtin_amdgcn_mfma_f32_16x16x32_bf16(af[3][g], bf, c3, 0, 0, 0);
            }
            float cbj = sCb[jc*64 + jt*16 + l15];
            #pragma unroll
            for (int r = 0; r < 4; ++r){
                ls[0][r] += __expf(fmaf(c0[r], INVT, cbj));
                ls[1][r] += __expf(fmaf(c1[r], INVT, cbj));
                ls[2][r] += __expf(fmaf(c2[r], INVT, cbj));
                ls[3][r] += __expf(fmaf(c3[r], INVT, cbj));
            }
        }
    }

    // reduce across the 16 lanes sharing each row
    #pragma unroll
    for (int s = 0; s < 4; ++s){
        #pragma unroll
        for (int r = 0; r < 4; ++r){
            #pragma unroll
            for (int m = 1; m < 16; m <<= 1)
                ls[s][r] += __shfl_xor(ls[s][r], m);
        }
    }
    if (l15 == 0){
        float* pp = psum + (((size_t)(b*4 + js)) << 10);
        int ibase = i0 + w*64 + lq*4;
        #pragma unroll
        for (int s = 0; s < 4; ++s){
            #pragma unroll
            for (int r = 0; r < 4; ++r)
                pp[ibase + s*16 + r] = ls[s][r];
        }
    }
}

// ---- banded positive max: one 16-lane group per row, <=5 candidate cols via idx.
__global__ __launch_bounds__(256) void pos_kernel(const short* __restrict__ E,
                                                  const short* __restrict__ V,
                                                  const int* __restrict__ mask,
                                                  const int* __restrict__ rank,
                                                  const int* __restrict__ idx,
                                                  const int* __restrict__ Tv,
                                                  float* __restrict__ pmax){
    int tid = threadIdx.x;
    int gl  = tid & 15;
    int rf  = (blockIdx.x * 256 + tid) >> 4;   // 0..32767
    int b   = rf >> 10;
    if (mask[rf] <= 0) return;

    int ri = rank[rf];
    int tv = Tv[b];
    int lo = ri - 2; if (lo < 0) lo = 0;
    int hi = ri + 2; if (hi > tv - 1) hi = tv - 1;

    const short* epp = E + (size_t)rf * 256 + gl * 16;
    float ev[16];
    {
        bf16x8 e0 = *(const bf16x8*)epp;
        bf16x8 e1 = *(const bf16x8*)(epp + 8);
        #pragma unroll
        for (int k = 0; k < 8; ++k){ ev[k] = bf2f(e0[k]); ev[8+k] = bf2f(e1[k]); }
    }
    float pm = -1e30f;
    for (int r = lo; r <= hi; ++r){
        int j = idx[b*1024 + r];
        const short* vpp = V + ((size_t)(b*1024) + j) * 256 + gl * 16;
        bf16x8 v0 = *(const bf16x8*)vpp;
        bf16x8 v1 = *(const bf16x8*)(vpp + 8);
        float s = 0.f;
        #pragma unroll
        for (int k = 0; k < 8; ++k){
            s = fmaf(ev[k],   bf2f(v0[k]), s);
            s = fmaf(ev[8+k], bf2f(v1[k]), s);
        }
        s += __shfl_xor(s, 1);
        s += __shfl_xor(s, 2);
        s += __shfl_xor(s, 4);
        s += __shfl_xor(s, 8);
        pm = fmaxf(pm, s);
    }
    if (gl == 0) pmax[rf] = pm * INVT;
}

// ---- per-batch reduce: sum over valid i of (log(sum_js psum) - pmax); gate Tv>=2
__global__ __launch_bounds__(256) void reduce_kernel(const float* __restrict__ psum,
                                                     const float* __restrict__ pmax,
                                                     const int* __restrict__ mask,
                                                     const int* __restrict__ Tv,
                                                     float* __restrict__ per_b){
    __shared__ float sred[4];
    int b = blockIdx.x, tid = threadIdx.x;
    float a = 0.f;
    const float* pp = psum + (((size_t)(b*4)) << 10);
    #pragma unroll
    for (int q = 0; q < 4; ++q){
        int i = q*256 + tid;
        int g = b*1024 + i;
        if (mask[g] > 0){
            float ps = pp[i] + pp[i + 1024] + pp[i + 2048] + pp[i + 3072];
            a += logf(ps) - pmax[g];
        }
    }
    #pragma unroll
    for (int m = 1; m < 64; m <<= 1) a += __shfl_xor(a, m);
    if ((tid & 63) == 0) sred[tid >> 6] = a;
    __syncthreads();
    if (tid == 0){
        float t = sred[0] + sred[1] + sred[2] + sred[3];
        int tv = Tv[b];
        per_b[b] = (tv >= 2) ? t / (float)tv : 0.f;
    }
}

// ---- final: out = sum_b per_b / 32
__global__ void final_kernel(const float* __restrict__ per_b,
                             float* __restrict__ out){
    int tid = threadIdx.x;
    float v = (tid < 32) ? per_b[tid] : 0.f;
    #pragma unroll
    for (int m = 1; m < 64; m <<= 1) v += __shfl_xor(v, m);
    if (tid == 0) out[0] = v / 32.0f;
}

extern "C" void kernel_launch(void* const* d_in, const int* in_sizes, int n_in,
                              void* d_out, int out_size, void* d_ws, size_t ws_size,
                              hipStream_t stream) {
    const float* eeg  = (const float*)d_in[0];
    const float* eye  = (const float*)d_in[1];
    const int*   mask = (const int*)d_in[2];
    const float* Weeg = (const float*)d_in[3];
    const float* Weye = (const float*)d_in[4];
    float* out = (float*)d_out;

    char* ws = (char*)d_ws;
    short* e_bf  = (short*)(ws);                       // 16 MiB
    short* v_bf  = (short*)(ws + 16777216);            // 16 MiB
    short* wbf   = (short*)(ws + 33554432);            // 256 KiB
    int*   rank  = (int*)  (ws + 33816576);            // 128 KiB
    int*   idx   = (int*)  (ws + 33947648);            // 128 KiB
    float* cb    = (float*)(ws + 34078720);            // 128 KiB
    float* psum  = (float*)(ws + 34209792);            // 512 KiB
    float* pmax  = (float*)(ws + 34734080);            // 128 KiB
    int*   Tv    = (int*)  (ws + 34865152);            // 128 B
    float* per_b = (float*)(ws + 34865280);            // 128 B

    prep_kernel<<<544, 256, 0, stream>>>(Weeg, Weye, mask, wbf, rank, idx, Tv, cb);
    proj_kernel<<<dim3(512, 2), 256, 0, stream>>>(eeg, eye, wbf, e_bf, v_bf);
    loss_kernel<<<dim3(4, 4, 32), 256, 0, stream>>>(e_bf, v_bf, cb, psum);
    pos_kernel<<<2048, 256, 0, stream>>>(e_bf, v_bf, mask, rank, idx, Tv, pmax);
    reduce_kernel<<<32, 256, 0, stream>>>(psum, pmax, mask, Tv, per_b);
    final_kernel<<<1, 64, 0, stream>>>(per_b, out);
}

// Round 4
// 171.568 us; speedup vs baseline: 1.3382x; 1.0345x over previous
//
#include <hip/hip_runtime.h>
#include <hip/hip_bf16.h>

// B=32, T=1024, D=256 fixed by the reference problem.
typedef __attribute__((ext_vector_type(8))) short bf16x8;
typedef __attribute__((ext_vector_type(4))) float f32x4;

#define INVT (1.0f/0.07f)

static __device__ __forceinline__ short f2bf(float f){
    unsigned int u = __float_as_uint(f);
    unsigned int r = (u + 0x7fffu + ((u >> 16) & 1u)) >> 16;
    return (short)r;
}
static __device__ __forceinline__ float bf2f(short s){
    return __uint_as_float(((unsigned int)(unsigned short)s) << 16);
}

// async global->LDS, 16B per lane; LDS dest = wave-uniform base + lane*16
static __device__ __forceinline__ void gld16(const void* g, void* l){
    __builtin_amdgcn_global_load_lds(
        (const __attribute__((address_space(1))) unsigned int*)g,
        (__attribute__((address_space(3))) unsigned int*)l, 16, 0, 0);
}

// ---- prep: blocks 0..511 convert W to bf16; blocks 512..543 per-batch rank scan
__global__ __launch_bounds__(256) void prep_kernel(const float* __restrict__ Weeg,
                                                   const float* __restrict__ Weye,
                                                   const int* __restrict__ mask,
                                                   short* __restrict__ Wout,
                                                   int* __restrict__ rank,
                                                   int* __restrict__ idx,
                                                   int* __restrict__ Tv,
                                                   float* __restrict__ cb){
    __shared__ int ssum[256];
    int tid = threadIdx.x;
    if (blockIdx.x < 512){
        int i = blockIdx.x * 256 + tid;
        float v = (i < 65536) ? Weeg[i] : Weye[i - 65536];
        Wout[i] = f2bf(v);
        return;
    }
    int b = blockIdx.x - 512;
    int local[4]; int s = 0;
    #pragma unroll
    for (int q = 0; q < 4; ++q){
        int t = tid*4 + q;
        local[q] = (mask[b*1024 + t] > 0) ? 1 : 0;
        s += local[q];
    }
    ssum[tid] = s;
    __syncthreads();
    for (int off = 1; off < 256; off <<= 1){
        int add = (tid >= off) ? ssum[tid - off] : 0;
        __syncthreads();
        ssum[tid] += add;
        __syncthreads();
    }
    int run = ssum[tid] - s;
    #pragma unroll
    for (int q = 0; q < 4; ++q){
        int t = tid*4 + q;
        int g = b*1024 + t;
        run += local[q];
        rank[g] = run - 1;
        cb[g]   = local[q] ? 0.0f : -1e9f;
        if (local[q]) idx[b*1024 + run - 1] = t;
    }
    if (tid == 255) Tv[b] = ssum[255];
}

// ---- fused projection + L2 normalize, both modalities (blockIdx.y selects).
__global__ __launch_bounds__(256, 3) void proj_kernel(const float* __restrict__ Aeeg,
                                                      const float* __restrict__ Aeye,
                                                      const short* __restrict__ Wbf,
                                                      short* __restrict__ Eout,
                                                      short* __restrict__ Vout){
    __shared__ short sW[64 * 264];
    int sel = blockIdx.y;
    const float* A   = sel ? Aeye : Aeeg;
    const short* W   = Wbf + sel * 65536;
    short*       Out = sel ? Vout : Eout;

    int tid = threadIdx.x;
    int w = tid >> 6, lane = tid & 63;
    int l15 = lane & 15, lq = lane >> 4;
    int kb  = lq * 8;
    int row0 = blockIdx.x * 64;

    // X-row fragments (B-operand)
    bf16x8 xf[8];
    {
        const float* ap = A + (size_t)(row0 + w*16 + l15) * 256 + kb;
        #pragma unroll
        for (int g = 0; g < 8; ++g){
            float4 x0 = *(const float4*)(ap + g*32);
            float4 x1 = *(const float4*)(ap + g*32 + 4);
            bf16x8 t;
            t[0]=f2bf(x0.x); t[1]=f2bf(x0.y); t[2]=f2bf(x0.z); t[3]=f2bf(x0.w);
            t[4]=f2bf(x1.x); t[5]=f2bf(x1.y); t[6]=f2bf(x1.z); t[7]=f2bf(x1.w);
            xf[g] = t;
        }
    }

    f32x4 acc[16];
    #pragma unroll
    for (int q = 0; q < 16; ++q) acc[q] = (f32x4){0.f,0.f,0.f,0.f};

    #pragma unroll
    for (int pass = 0; pass < 4; ++pass){
        if (pass) __syncthreads();
        #pragma unroll
        for (int p = 0; p < 8; ++p){
            int flat = p*2048 + tid*8;
            int r = flat >> 8, c = flat & 255;
            *(int4*)&sW[r*264 + c] = *(const int4*)(W + (size_t)(pass*64 + r)*256 + c);
        }
        __syncthreads();
        #pragma unroll
        for (int nt = 0; nt < 4; ++nt){
            f32x4 c = acc[pass*4 + nt];
            const short* wp = &sW[(nt*16 + l15) * 264 + kb];
            #pragma unroll
            for (int g = 0; g < 8; ++g){
                bf16x8 wf = *(const bf16x8*)(wp + g*32);
                c = __builtin_amdgcn_mfma_f32_16x16x32_bf16(wf, xf[g], c, 0, 0, 0);
            }
            acc[pass*4 + nt] = c;
        }
    }

    float ss = 0.f;
    #pragma unroll
    for (int q = 0; q < 16; ++q){
        #pragma unroll
        for (int r = 0; r < 4; ++r){ float x = acc[q][r]; ss += x*x; }
    }
    ss += __shfl_xor(ss, 16);
    ss += __shfl_xor(ss, 32);
    float scale = 1.0f / fmaxf(sqrtf(ss), 1e-12f);

    short* op = Out + (size_t)(row0 + w*16 + l15) * 256 + lq*4;
    #pragma unroll
    for (int q = 0; q < 16; ++q){
        short4 pk;
        pk.x = f2bf(acc[q][0] * scale);
        pk.y = f2bf(acc[q][1] * scale);
        pk.z = f2bf(acc[q][2] * scale);
        pk.w = f2bf(acc[q][3] * scale);
        *(short4*)(op + ((q >> 2) * 64 + (q & 3) * 16)) = pk;
    }
}

// ---- loss: m97-style dual-LDS GEMM. Block = 128 i-rows x 128 j-cols, 4 waves 2x2,
// each wave 64x64 (16 f32x4 accs). K=256 in 4 chunks of 64 via global_load_lds w=16.
// Epilogue: exp(s/T + cb) row-sums -> psum[b][jb*2+wj][i] (16 slices per b).
__global__ __launch_bounds__(256, 4) void loss_kernel(const short* __restrict__ E,
                                                      const short* __restrict__ V,
                                                      const float* __restrict__ cb,
                                                      float* __restrict__ psum){
    __shared__ short sE[128 * 64];
    __shared__ short sV[128 * 64];

    int i0 = blockIdx.x * 128;
    int j0 = blockIdx.y * 128;
    int b  = blockIdx.z;

    int tid = threadIdx.x;
    int w = tid >> 6, lane = tid & 63;
    int wi = w >> 1, wj = w & 1;
    int l15 = lane & 15, lq = lane >> 4;
    int kb = lq * 8;

    // this wave stages rows [w*32, w*32+32) of each tile; 8 rows per issue
    const short* Eg = E + ((size_t)b*1024 + i0 + w*32 + (lane>>3))*256 + (lane&7)*8;
    const short* Vg = V + ((size_t)b*1024 + j0 + w*32 + (lane>>3))*256 + (lane&7)*8;
    short* sEw = &sE[(w*32)*64];
    short* sVw = &sV[(w*32)*64];

    float cbv[4];
    #pragma unroll
    for (int jj = 0; jj < 4; ++jj)
        cbv[jj] = cb[b*1024 + j0 + wj*64 + jj*16 + l15];

    f32x4 acc[4][4];
    #pragma unroll
    for (int ii = 0; ii < 4; ++ii)
        #pragma unroll
        for (int jj = 0; jj < 4; ++jj) acc[ii][jj] = (f32x4){0.f,0.f,0.f,0.f};

    #pragma unroll
    for (int kc = 0; kc < 4; ++kc){
        __syncthreads();
        #pragma unroll
        for (int p = 0; p < 4; ++p){
            gld16(Eg + kc*64 + p*2048, sEw + p*512);
            gld16(Vg + kc*64 + p*2048, sVw + p*512);
        }
        __syncthreads();

        #pragma unroll
        for (int ks = 0; ks < 2; ++ks){
            bf16x8 af[4], bf[4];
            #pragma unroll
            for (int t = 0; t < 4; ++t){
                af[t] = *(const bf16x8*)&sE[(wi*64 + t*16 + l15)*64 + ks*32 + kb];
                bf[t] = *(const bf16x8*)&sV[(wj*64 + t*16 + l15)*64 + ks*32 + kb];
            }
            #pragma unroll
            for (int ii = 0; ii < 4; ++ii)
                #pragma unroll
                for (int jj = 0; jj < 4; ++jj)
                    acc[ii][jj] = __builtin_amdgcn_mfma_f32_16x16x32_bf16(af[ii], bf[jj], acc[ii][jj], 0, 0, 0);
        }
    }

    // epilogue: ls[ii][r] = sum_jj exp(acc*INVT + cb[j])
    float ls[4][4];
    #pragma unroll
    for (int ii = 0; ii < 4; ++ii){
        #pragma unroll
        for (int r = 0; r < 4; ++r){
            float s = 0.f;
            #pragma unroll
            for (int jj = 0; jj < 4; ++jj)
                s += __expf(fmaf(acc[ii][jj][r], INVT, cbv[jj]));
            ls[ii][r] = s;
        }
    }
    #pragma unroll
    for (int ii = 0; ii < 4; ++ii){
        #pragma unroll
        for (int r = 0; r < 4; ++r){
            float v = ls[ii][r];
            v += __shfl_xor(v, 1);
            v += __shfl_xor(v, 2);
            v += __shfl_xor(v, 4);
            v += __shfl_xor(v, 8);
            ls[ii][r] = v;
        }
    }
    if (l15 == 0){
        float* pp = psum + (((size_t)(b*16 + blockIdx.y*2 + wj)) << 10);
        int ibase = i0 + wi*64 + lq*4;
        #pragma unroll
        for (int ii = 0; ii < 4; ++ii){
            #pragma unroll
            for (int r = 0; r < 4; ++r)
                pp[ibase + ii*16 + r] = ls[ii][r];
        }
    }
}

// ---- banded positive max: one 16-lane group per row, <=5 candidate cols via idx.
__global__ __launch_bounds__(256) void pos_kernel(const short* __restrict__ E,
                                                  const short* __restrict__ V,
                                                  const int* __restrict__ mask,
                                                  const int* __restrict__ rank,
                                                  const int* __restrict__ idx,
                                                  const int* __restrict__ Tv,
                                                  float* __restrict__ pmax){
    int tid = threadIdx.x;
    int gl  = tid & 15;
    int rf  = (blockIdx.x * 256 + tid) >> 4;   // 0..32767
    int b   = rf >> 10;
    if (mask[rf] <= 0) return;

    int ri = rank[rf];
    int tv = Tv[b];
    int lo = ri - 2; if (lo < 0) lo = 0;
    int hi = ri + 2; if (hi > tv - 1) hi = tv - 1;

    const short* epp = E + (size_t)rf * 256 + gl * 16;
    float ev[16];
    {
        bf16x8 e0 = *(const bf16x8*)epp;
        bf16x8 e1 = *(const bf16x8*)(epp + 8);
        #pragma unroll
        for (int k = 0; k < 8; ++k){ ev[k] = bf2f(e0[k]); ev[8+k] = bf2f(e1[k]); }
    }
    float pm = -1e30f;
    for (int r = lo; r <= hi; ++r){
        int j = idx[b*1024 + r];
        const short* vpp = V + ((size_t)(b*1024) + j) * 256 + gl * 16;
        bf16x8 v0 = *(const bf16x8*)vpp;
        bf16x8 v1 = *(const bf16x8*)(vpp + 8);
        float s = 0.f;
        #pragma unroll
        for (int k = 0; k < 8; ++k){
            s = fmaf(ev[k],   bf2f(v0[k]), s);
            s = fmaf(ev[8+k], bf2f(v1[k]), s);
        }
        s += __shfl_xor(s, 1);
        s += __shfl_xor(s, 2);
        s += __shfl_xor(s, 4);
        s += __shfl_xor(s, 8);
        pm = fmaxf(pm, s);
    }
    if (gl == 0) pmax[rf] = pm * INVT;
}

// ---- per-batch reduce: sum over valid i of (log(sum_s psum) - pmax); gate Tv>=2
__global__ __launch_bounds__(256) void reduce_kernel(const float* __restrict__ psum,
                                                     const float* __restrict__ pmax,
                                                     const int* __restrict__ mask,
                                                     const int* __restrict__ Tv,
                                                     float* __restrict__ per_b){
    __shared__ float sred[4];
    int b = blockIdx.x, tid = threadIdx.x;
    float a = 0.f;
    const float* pp = psum + ((size_t)b << 14);
    #pragma unroll
    for (int q = 0; q < 4; ++q){
        int i = q*256 + tid;
        int g = b*1024 + i;
        if (mask[g] > 0){
            float ps = 0.f;
            #pragma unroll
            for (int s = 0; s < 16; ++s) ps += pp[i + (s << 10)];
            a += logf(ps) - pmax[g];
        }
    }
    #pragma unroll
    for (int m = 1; m < 64; m <<= 1) a += __shfl_xor(a, m);
    if ((tid & 63) == 0) sred[tid >> 6] = a;
    __syncthreads();
    if (tid == 0){
        float t = sred[0] + sred[1] + sred[2] + sred[3];
        int tv = Tv[b];
        per_b[b] = (tv >= 2) ? t / (float)tv : 0.f;
    }
}

// ---- final: out = sum_b per_b / 32
__global__ void final_kernel(const float* __restrict__ per_b,
                             float* __restrict__ out){
    int tid = threadIdx.x;
    float v = (tid < 32) ? per_b[tid] : 0.f;
    #pragma unroll
    for (int m = 1; m < 64; m <<= 1) v += __shfl_xor(v, m);
    if (tid == 0) out[0] = v / 32.0f;
}

extern "C" void kernel_launch(void* const* d_in, const int* in_sizes, int n_in,
                              void* d_out, int out_size, void* d_ws, size_t ws_size,
                              hipStream_t stream) {
    const float* eeg  = (const float*)d_in[0];
    const float* eye  = (const float*)d_in[1];
    const int*   mask = (const int*)d_in[2];
    const float* Weeg = (const float*)d_in[3];
    const float* Weye = (const float*)d_in[4];
    float* out = (float*)d_out;

    char* ws = (char*)d_ws;
    short* e_bf  = (short*)(ws);                       // 16 MiB
    short* v_bf  = (short*)(ws + 16777216);            // 16 MiB
    short* wbf   = (short*)(ws + 33554432);            // 256 KiB
    int*   rank  = (int*)  (ws + 33816576);            // 128 KiB
    int*   idx   = (int*)  (ws + 33947648);            // 128 KiB
    float* cb    = (float*)(ws + 34078720);            // 128 KiB
    float* psum  = (float*)(ws + 34209792);            // 2 MiB (32 b x 16 slices x 1024)
    float* pmax  = (float*)(ws + 36306944);            // 128 KiB
    int*   Tv    = (int*)  (ws + 36438016);            // 128 B
    float* per_b = (float*)(ws + 36438144);            // 128 B

    prep_kernel<<<544, 256, 0, stream>>>(Weeg, Weye, mask, wbf, rank, idx, Tv, cb);
    proj_kernel<<<dim3(512, 2), 256, 0, stream>>>(eeg, eye, wbf, e_bf, v_bf);
    loss_kernel<<<dim3(8, 8, 32), 256, 0, stream>>>(e_bf, v_bf, cb, psum);
    pos_kernel<<<2048, 256, 0, stream>>>(e_bf, v_bf, mask, rank, idx, Tv, pmax);
    reduce_kernel<<<32, 256, 0, stream>>>(psum, pmax, mask, Tv, per_b);
    final_kernel<<<1, 64, 0, stream>>>(per_b, out);
}

// Round 5
// 170.503 us; speedup vs baseline: 1.3465x; 1.0062x over previous
//
#include <hip/hip_runtime.h>
#include <hip/hip_bf16.h>

// B=32, T=1024, D=256 fixed by the reference problem.
typedef __attribute__((ext_vector_type(8))) short bf16x8;
typedef __attribute__((ext_vector_type(4))) float f32x4;

#define INVT (1.0f/0.07f)

static __device__ __forceinline__ short f2bf(float f){
    unsigned int u = __float_as_uint(f);
    unsigned int r = (u + 0x7fffu + ((u >> 16) & 1u)) >> 16;
    return (short)r;
}
static __device__ __forceinline__ float bf2f(short s){
    return __uint_as_float(((unsigned int)(unsigned short)s) << 16);
}

// async global->LDS, 16B per lane; LDS dest = wave-uniform base + lane*16
static __device__ __forceinline__ void gld16(const void* g, void* l){
    __builtin_amdgcn_global_load_lds(
        (const __attribute__((address_space(1))) unsigned int*)g,
        (__attribute__((address_space(3))) unsigned int*)l, 16, 0, 0);
}

// ---- prep: blocks 0..511 convert W to bf16; blocks 512..543 per-batch rank scan
__global__ __launch_bounds__(256) void prep_kernel(const float* __restrict__ Weeg,
                                                   const float* __restrict__ Weye,
                                                   const int* __restrict__ mask,
                                                   short* __restrict__ Wout,
                                                   int* __restrict__ rank,
                                                   int* __restrict__ idx,
                                                   int* __restrict__ Tv,
                                                   float* __restrict__ cb){
    __shared__ int ssum[256];
    int tid = threadIdx.x;
    if (blockIdx.x < 512){
        int i = blockIdx.x * 256 + tid;
        float v = (i < 65536) ? Weeg[i] : Weye[i - 65536];
        Wout[i] = f2bf(v);
        return;
    }
    int b = blockIdx.x - 512;
    int local[4]; int s = 0;
    #pragma unroll
    for (int q = 0; q < 4; ++q){
        int t = tid*4 + q;
        local[q] = (mask[b*1024 + t] > 0) ? 1 : 0;
        s += local[q];
    }
    ssum[tid] = s;
    __syncthreads();
    for (int off = 1; off < 256; off <<= 1){
        int add = (tid >= off) ? ssum[tid - off] : 0;
        __syncthreads();
        ssum[tid] += add;
        __syncthreads();
    }
    int run = ssum[tid] - s;
    #pragma unroll
    for (int q = 0; q < 4; ++q){
        int t = tid*4 + q;
        int g = b*1024 + t;
        run += local[q];
        rank[g] = run - 1;
        cb[g]   = local[q] ? 0.0f : -1e9f;
        if (local[q]) idx[b*1024 + run - 1] = t;
    }
    if (tid == 255) Tv[b] = ssum[255];
}

// ---- fused projection + L2 normalize, both modalities (blockIdx.y selects).
// W staged via global_load_lds(16B) into XOR-swizzled unpadded LDS (32 KB).
// 64 x-rows/block, 4 waves x 16 rows, each wave computes 16 rows x 256 e-cols.
__global__ __launch_bounds__(256, 3) void proj_kernel(const float* __restrict__ Aeeg,
                                                      const float* __restrict__ Aeye,
                                                      const short* __restrict__ Wbf,
                                                      short* __restrict__ Eout,
                                                      short* __restrict__ Vout){
    __shared__ short sW[64 * 256];     // unpadded; XOR-swizzled in 16B blocks
    int sel = blockIdx.y;
    const float* A   = sel ? Aeye : Aeeg;
    const short* W   = Wbf + sel * 65536;
    short*       Out = sel ? Vout : Eout;

    int tid = threadIdx.x;
    int w = tid >> 6, lane = tid & 63;
    int l15 = lane & 15, lq = lane >> 4;
    int kb  = lq * 8;
    int row0 = blockIdx.x * 64;

    // X-row fragments (B-operand), f32 -> bf16
    bf16x8 xf[8];
    {
        const float* ap = A + (size_t)(row0 + w*16 + l15) * 256 + kb;
        #pragma unroll
        for (int g = 0; g < 8; ++g){
            float4 x0 = *(const float4*)(ap + g*32);
            float4 x1 = *(const float4*)(ap + g*32 + 4);
            bf16x8 t;
            t[0]=f2bf(x0.x); t[1]=f2bf(x0.y); t[2]=f2bf(x0.z); t[3]=f2bf(x0.w);
            t[4]=f2bf(x1.x); t[5]=f2bf(x1.y); t[6]=f2bf(x1.z); t[7]=f2bf(x1.w);
            xf[g] = t;
        }
    }

    f32x4 acc[16];
    #pragma unroll
    for (int q = 0; q < 16; ++q) acc[q] = (f32x4){0.f,0.f,0.f,0.f};

    int ro   = lane >> 5;        // 0..1: row within a 1KB gld16 issue
    int cb_s = lane & 31;        // 16B col-block within a 512B row
    int s7   = l15 & 7;

    #pragma unroll
    for (int pass = 0; pass < 4; ++pass){
        if (pass) __syncthreads();
        // stage W rows [pass*64, +64): each wave 16 rows, 2 rows per issue
        #pragma unroll
        for (int p = 0; p < 8; ++p){
            int rl  = w*16 + p*2 + ro;                 // LDS row index
            int cbg = cb_s ^ ((p*2 + ro) & 7);         // swizzled global col-block
            gld16(W + (size_t)(pass*64 + rl)*256 + cbg*8,
                  &sW[(w*16 + p*2) * 256]);
        }
        __syncthreads();
        #pragma unroll
        for (int nt = 0; nt < 4; ++nt){
            f32x4 c = acc[pass*4 + nt];
            int rbase = (nt*16 + l15) * 256;
            #pragma unroll
            for (int g = 0; g < 8; ++g){
                bf16x8 wf = *(const bf16x8*)&sW[rbase + (((g*4 + lq) ^ s7) << 3)];
                c = __builtin_amdgcn_mfma_f32_16x16x32_bf16(wf, xf[g], c, 0, 0, 0);
            }
            acc[pass*4 + nt] = c;
        }
    }

    // D[e][xrow]: lane holds xrow = l15, e = (pass*4+nt)*16 + lq*4 + r
    float ss = 0.f;
    #pragma unroll
    for (int q = 0; q < 16; ++q){
        #pragma unroll
        for (int r = 0; r < 4; ++r){ float x = acc[q][r]; ss += x*x; }
    }
    ss += __shfl_xor(ss, 16);
    ss += __shfl_xor(ss, 32);
    float scale = 1.0f / fmaxf(sqrtf(ss), 1e-12f);

    short* op = Out + (size_t)(row0 + w*16 + l15) * 256 + lq*4;
    #pragma unroll
    for (int q = 0; q < 16; ++q){
        short4 pk;
        pk.x = f2bf(acc[q][0] * scale);
        pk.y = f2bf(acc[q][1] * scale);
        pk.z = f2bf(acc[q][2] * scale);
        pk.w = f2bf(acc[q][3] * scale);
        *(short4*)(op + ((q >> 2) * 64 + (q & 3) * 16)) = pk;
    }
}

// ---- loss: dual-LDS GEMM, 128x128 tile, 4 waves 2x2, each wave 64x64.
// K=256 in 4 chunks of 64 via global_load_lds(16B) into XOR-swizzled LDS.
// Epilogue: exp(s/T + cb) row-sums -> psum[b][jb*2+wj][i] (16 slices per b).
__global__ __launch_bounds__(256, 4) void loss_kernel(const short* __restrict__ E,
                                                      const short* __restrict__ V,
                                                      const float* __restrict__ cb,
                                                      float* __restrict__ psum){
    __shared__ short sE[128 * 64];     // unpadded; XOR-swizzled in 16B blocks
    __shared__ short sV[128 * 64];

    int i0 = blockIdx.x * 128;
    int j0 = blockIdx.y * 128;
    int b  = blockIdx.z;

    int tid = threadIdx.x;
    int w = tid >> 6, lane = tid & 63;
    int wi = w >> 1, wj = w & 1;
    int l15 = lane & 15, lq = lane >> 4;
    int s7 = l15 & 7;

    // staging: wave w stages rows [w*32, +32); 8 rows x 128B per issue.
    // swizzle: LDS slot (row, cb) holds global (row, cb ^ (row&7));
    // per-lane: row_off = lane>>3, cb = lane&7 -> global col-block = (lane&7)^(lane>>3)
    int swz = ((lane & 7) ^ (lane >> 3)) * 8;
    const short* Eg = E + ((size_t)b*1024 + i0 + w*32 + (lane>>3))*256 + swz;
    const short* Vg = V + ((size_t)b*1024 + j0 + w*32 + (lane>>3))*256 + swz;
    short* sEw = &sE[(w*32)*64];
    short* sVw = &sV[(w*32)*64];

    float cbv[4];
    #pragma unroll
    for (int jj = 0; jj < 4; ++jj)
        cbv[jj] = cb[b*1024 + j0 + wj*64 + jj*16 + l15];

    f32x4 acc[4][4];
    #pragma unroll
    for (int ii = 0; ii < 4; ++ii)
        #pragma unroll
        for (int jj = 0; jj < 4; ++jj) acc[ii][jj] = (f32x4){0.f,0.f,0.f,0.f};

    #pragma unroll
    for (int kc = 0; kc < 4; ++kc){
        __syncthreads();
        #pragma unroll
        for (int p = 0; p < 4; ++p){
            gld16(Eg + kc*64 + p*2048, sEw + p*512);
            gld16(Vg + kc*64 + p*2048, sVw + p*512);
        }
        __syncthreads();

        #pragma unroll
        for (int ks = 0; ks < 2; ++ks){
            bf16x8 af[4], bf[4];
            #pragma unroll
            for (int t = 0; t < 4; ++t){
                int co = (((ks*4 + lq) ^ s7)) << 3;
                af[t] = *(const bf16x8*)&sE[(wi*64 + t*16 + l15)*64 + co];
                bf[t] = *(const bf16x8*)&sV[(wj*64 + t*16 + l15)*64 + co];
            }
            #pragma unroll
            for (int ii = 0; ii < 4; ++ii)
                #pragma unroll
                for (int jj = 0; jj < 4; ++jj)
                    acc[ii][jj] = __builtin_amdgcn_mfma_f32_16x16x32_bf16(af[ii], bf[jj], acc[ii][jj], 0, 0, 0);
        }
    }

    // epilogue: ls[ii][r] = sum_jj exp(acc*INVT + cb[j])
    float ls[4][4];
    #pragma unroll
    for (int ii = 0; ii < 4; ++ii){
        #pragma unroll
        for (int r = 0; r < 4; ++r){
            float s = 0.f;
            #pragma unroll
            for (int jj = 0; jj < 4; ++jj)
                s += __expf(fmaf(acc[ii][jj][r], INVT, cbv[jj]));
            ls[ii][r] = s;
        }
    }
    #pragma unroll
    for (int ii = 0; ii < 4; ++ii){
        #pragma unroll
        for (int r = 0; r < 4; ++r){
            float v = ls[ii][r];
            v += __shfl_xor(v, 1);
            v += __shfl_xor(v, 2);
            v += __shfl_xor(v, 4);
            v += __shfl_xor(v, 8);
            ls[ii][r] = v;
        }
    }
    if (l15 == 0){
        float* pp = psum + (((size_t)(b*16 + blockIdx.y*2 + wj)) << 10);
        int ibase = i0 + wi*64 + lq*4;
        #pragma unroll
        for (int ii = 0; ii < 4; ++ii){
            #pragma unroll
            for (int r = 0; r < 4; ++r)
                pp[ibase + ii*16 + r] = ls[ii][r];
        }
    }
}

// ---- banded positive max: one 16-lane group per row, <=5 candidate cols via idx.
__global__ __launch_bounds__(256) void pos_kernel(const short* __restrict__ E,
                                                  const short* __restrict__ V,
                                                  const int* __restrict__ mask,
                                                  const int* __restrict__ rank,
                                                  const int* __restrict__ idx,
                                                  const int* __restrict__ Tv,
                                                  float* __restrict__ pmax){
    int tid = threadIdx.x;
    int gl  = tid & 15;
    int rf  = (blockIdx.x * 256 + tid) >> 4;   // 0..32767
    int b   = rf >> 10;
    if (mask[rf] <= 0) return;

    int ri = rank[rf];
    int tv = Tv[b];
    int lo = ri - 2; if (lo < 0) lo = 0;
    int hi = ri + 2; if (hi > tv - 1) hi = tv - 1;

    const short* epp = E + (size_t)rf * 256 + gl * 16;
    float ev[16];
    {
        bf16x8 e0 = *(const bf16x8*)epp;
        bf16x8 e1 = *(const bf16x8*)(epp + 8);
        #pragma unroll
        for (int k = 0; k < 8; ++k){ ev[k] = bf2f(e0[k]); ev[8+k] = bf2f(e1[k]); }
    }
    float pm = -1e30f;
    for (int r = lo; r <= hi; ++r){
        int j = idx[b*1024 + r];
        const short* vpp = V + ((size_t)(b*1024) + j) * 256 + gl * 16;
        bf16x8 v0 = *(const bf16x8*)vpp;
        bf16x8 v1 = *(const bf16x8*)(vpp + 8);
        float s = 0.f;
        #pragma unroll
        for (int k = 0; k < 8; ++k){
            s = fmaf(ev[k],   bf2f(v0[k]), s);
            s = fmaf(ev[8+k], bf2f(v1[k]), s);
        }
        s += __shfl_xor(s, 1);
        s += __shfl_xor(s, 2);
        s += __shfl_xor(s, 4);
        s += __shfl_xor(s, 8);
        pm = fmaxf(pm, s);
    }
    if (gl == 0) pmax[rf] = pm * INVT;
}

// ---- per-batch reduce: sum over valid i of (log(sum_s psum) - pmax); gate Tv>=2
__global__ __launch_bounds__(256) void reduce_kernel(const float* __restrict__ psum,
                                                     const float* __restrict__ pmax,
                                                     const int* __restrict__ mask,
                                                     const int* __restrict__ Tv,
                                                     float* __restrict__ per_b){
    __shared__ float sred[4];
    int b = blockIdx.x, tid = threadIdx.x;
    float a = 0.f;
    const float* pp = psum + ((size_t)b << 14);
    #pragma unroll
    for (int q = 0; q < 4; ++q){
        int i = q*256 + tid;
        int g = b*1024 + i;
        if (mask[g] > 0){
            float ps = 0.f;
            #pragma unroll
            for (int s = 0; s < 16; ++s) ps += pp[i + (s << 10)];
            a += logf(ps) - pmax[g];
        }
    }
    #pragma unroll
    for (int m = 1; m < 64; m <<= 1) a += __shfl_xor(a, m);
    if ((tid & 63) == 0) sred[tid >> 6] = a;
    __syncthreads();
    if (tid == 0){
        float t = sred[0] + sred[1] + sred[2] + sred[3];
        int tv = Tv[b];
        per_b[b] = (tv >= 2) ? t / (float)tv : 0.f;
    }
}

// ---- final: out = sum_b per_b / 32
__global__ void final_kernel(const float* __restrict__ per_b,
                             float* __restrict__ out){
    int tid = threadIdx.x;
    float v = (tid < 32) ? per_b[tid] : 0.f;
    #pragma unroll
    for (int m = 1; m < 64; m <<= 1) v += __shfl_xor(v, m);
    if (tid == 0) out[0] = v / 32.0f;
}

extern "C" void kernel_launch(void* const* d_in, const int* in_sizes, int n_in,
                              void* d_out, int out_size, void* d_ws, size_t ws_size,
                              hipStream_t stream) {
    const float* eeg  = (const float*)d_in[0];
    const float* eye  = (const float*)d_in[1];
    const int*   mask = (const int*)d_in[2];
    const float* Weeg = (const float*)d_in[3];
    const float* Weye = (const float*)d_in[4];
    float* out = (float*)d_out;

    char* ws = (char*)d_ws;
    short* e_bf  = (short*)(ws);                       // 16 MiB
    short* v_bf  = (short*)(ws + 16777216);            // 16 MiB
    short* wbf   = (short*)(ws + 33554432);            // 256 KiB
    int*   rank  = (int*)  (ws + 33816576);            // 128 KiB
    int*   idx   = (int*)  (ws + 33947648);            // 128 KiB
    float* cb    = (float*)(ws + 34078720);            // 128 KiB
    float* psum  = (float*)(ws + 34209792);            // 2 MiB (32 b x 16 slices x 1024)
    float* pmax  = (float*)(ws + 36306944);            // 128 KiB
    int*   Tv    = (int*)  (ws + 36438016);            // 128 B
    float* per_b = (float*)(ws + 36438144);            // 128 B

    prep_kernel<<<544, 256, 0, stream>>>(Weeg, Weye, mask, wbf, rank, idx, Tv, cb);
    proj_kernel<<<dim3(512, 2), 256, 0, stream>>>(eeg, eye, wbf, e_bf, v_bf);
    loss_kernel<<<dim3(8, 8, 32), 256, 0, stream>>>(e_bf, v_bf, cb, psum);
    pos_kernel<<<2048, 256, 0, stream>>>(e_bf, v_bf, mask, rank, idx, Tv, pmax);
    reduce_kernel<<<32, 256, 0, stream>>>(psum, pmax, mask, Tv, per_b);
    final_kernel<<<1, 64, 0, stream>>>(per_b, out);
}